// Round 1
// baseline (109.767 us; speedup 1.0000x reference)
//
#include <hip/hip_runtime.h>
#include <math.h>

#define HW 65536            // 256*256 elements per (b,c) plane
#define HW4 16384           // float4 per plane
#define NPLANES 768         // 64*12
#define NQ 4
#define NCH 12

// ---------------- Kernel 1: per-plane mean ----------------
__global__ __launch_bounds__(512) void mean_kernel(const float* __restrict__ x,
                                                   float* __restrict__ y) {
    const int plane = blockIdx.x;
    const float4* p = reinterpret_cast<const float4*>(x) + (size_t)plane * HW4;
    float sum = 0.f;
    for (int i = threadIdx.x; i < HW4; i += blockDim.x) {
        float4 v = p[i];
        sum += (v.x + v.y) + (v.z + v.w);
    }
    // wave (64-lane) reduce
    #pragma unroll
    for (int off = 32; off > 0; off >>= 1) sum += __shfl_down(sum, off);
    __shared__ float wsum[8];
    const int lane = threadIdx.x & 63;
    const int wid  = threadIdx.x >> 6;
    if (lane == 0) wsum[wid] = sum;
    __syncthreads();
    if (threadIdx.x == 0) {
        float t = 0.f;
        #pragma unroll
        for (int i = 0; i < 8; ++i) t += wsum[i];
        y[plane] = t * (1.0f / (float)HW);
    }
}

// ---------------- Kernel 2: VQC + FC + sigmoid ----------------
// One thread per batch element; 16 complex amplitudes in registers.
// Flat amplitude index: bit (3-q) holds qubit q (q0 = MSB).
__device__ __forceinline__ void apply_rz(float* sr, float* si, int mask, float theta) {
    float c, s;
    __sincosf(0.5f * theta, &s, &c);
    #pragma unroll
    for (int i = 0; i < 16; ++i) {
        float r = sr[i], im = si[i];
        if (i & mask) {            // multiply by e^{+i t/2} = (c, +s)
            sr[i] = r * c - im * s;
            si[i] = im * c + r * s;
        } else {                   // multiply by e^{-i t/2} = (c, -s)
            sr[i] = r * c + im * s;
            si[i] = im * c - r * s;
        }
    }
}

__device__ __forceinline__ void apply_ry(float* sr, float* si, int mask, float theta) {
    float c, s;
    __sincosf(0.5f * theta, &s, &c);
    #pragma unroll
    for (int i = 0; i < 16; ++i) {
        if (i & mask) continue;
        int j = i | mask;
        float r0 = sr[i], i0 = si[i], r1 = sr[j], i1 = si[j];
        sr[i] = c * r0 - s * r1;  si[i] = c * i0 - s * i1;
        sr[j] = s * r0 + c * r1;  si[j] = s * i0 + c * i1;
    }
}

__device__ __forceinline__ void apply_cnot(float* sr, float* si, int mc, int mt) {
    #pragma unroll
    for (int i = 0; i < 16; ++i) {
        if ((i & mc) && !(i & mt)) {
            int j = i | mt;
            float tr = sr[i], ti = si[i];
            sr[i] = sr[j]; si[i] = si[j];
            sr[j] = tr;    si[j] = ti;
        }
    }
}

__device__ __forceinline__ void apply_u3(float* sr, float* si, int mask,
                                         float theta, float phi, float lam) {
    float c = __cosf(0.5f * theta), s = __sinf(0.5f * theta);
    float cl, sl, cp, sp, cpl, spl;
    __sincosf(lam, &sl, &cl);
    __sincosf(phi, &sp, &cp);
    __sincosf(phi + lam, &spl, &cpl);
    // U = [[c, -e^{i lam} s], [e^{i phi} s, e^{i (phi+lam)} c]]
    float u01r = -cl * s, u01i = -sl * s;
    float u10r =  cp * s, u10i =  sp * s;
    float u11r =  cpl * c, u11i = spl * c;
    #pragma unroll
    for (int i = 0; i < 16; ++i) {
        if (i & mask) continue;
        int j = i | mask;
        float r0 = sr[i], i0 = si[i], r1 = sr[j], i1 = si[j];
        // a0' = c*a0 + u01*a1
        sr[i] = c * r0 + (u01r * r1 - u01i * i1);
        si[i] = c * i0 + (u01r * i1 + u01i * r1);
        // a1' = u10*a0 + u11*a1
        sr[j] = (u10r * r0 - u10i * i0) + (u11r * r1 - u11i * i1);
        si[j] = (u10r * i0 + u10i * r0) + (u11r * i1 + u11i * r1);
    }
}

__global__ __launch_bounds__(64) void vqc_kernel(const float* __restrict__ y,    // [64,12]
                                                 const float* __restrict__ w,    // [1,4,3]
                                                 const float* __restrict__ fcw,  // [12,4]
                                                 const float* __restrict__ fcb,  // [12]
                                                 float* __restrict__ att) {      // [64,12]
    const int b = threadIdx.x;      // 64 batch elements, one wave
    float sr[16], si[16];
    #pragma unroll
    for (int i = 0; i < 16; ++i) { sr[i] = 0.25f; si[i] = 0.f; }

    // Encoding: RZ, RY, RZ on each qubit
    #pragma unroll
    for (int q = 0; q < NQ; ++q) {
        const int mask = 1 << (3 - q);
        float t0 = y[b * NCH + q * 3 + 0];
        float t1 = y[b * NCH + q * 3 + 1];
        float t2 = y[b * NCH + q * 3 + 2];
        apply_rz(sr, si, mask, t0);
        apply_ry(sr, si, mask, t1);
        apply_rz(sr, si, mask, t2);
    }

    // Layer 0: CNOT ring (0,1),(1,2),(2,3),(3,0) then U3 on each qubit
    apply_cnot(sr, si, 1 << 3, 1 << 2);
    apply_cnot(sr, si, 1 << 2, 1 << 1);
    apply_cnot(sr, si, 1 << 1, 1 << 0);
    apply_cnot(sr, si, 1 << 0, 1 << 3);
    #pragma unroll
    for (int q = 0; q < NQ; ++q) {
        const int mask = 1 << (3 - q);
        apply_u3(sr, si, mask, w[q * 3 + 0], w[q * 3 + 1], w[q * 3 + 2]);
    }

    // Z expectations
    float z[NQ];
    #pragma unroll
    for (int q = 0; q < NQ; ++q) {
        const int mask = 1 << (3 - q);
        float acc = 0.f;
        #pragma unroll
        for (int i = 0; i < 16; ++i) {
            float p = sr[i] * sr[i] + si[i] * si[i];
            acc += (i & mask) ? -p : p;
        }
        z[q] = acc;
    }

    // FC + sigmoid
    #pragma unroll
    for (int ch = 0; ch < NCH; ++ch) {
        float a = fcb[ch];
        #pragma unroll
        for (int q = 0; q < NQ; ++q) a += z[q] * fcw[ch * NQ + q];
        att[b * NCH + ch] = 1.0f / (1.0f + expf(-a));
    }
}

// ---------------- Kernel 3: broadcast scale ----------------
__global__ __launch_bounds__(256) void scale_kernel(const float* __restrict__ x,
                                                    const float* __restrict__ att,
                                                    float* __restrict__ out,
                                                    long n4) {
    long i = (long)blockIdx.x * blockDim.x + threadIdx.x;
    const long stride = (long)gridDim.x * blockDim.x;
    const float4* xi = reinterpret_cast<const float4*>(x);
    float4* oi = reinterpret_cast<float4*>(out);
    for (; i < n4; i += stride) {
        float a = att[i >> 14];     // 16384 float4 per plane; wave-uniform
        float4 v = xi[i];
        v.x *= a; v.y *= a; v.z *= a; v.w *= a;
        oi[i] = v;
    }
}

extern "C" void kernel_launch(void* const* d_in, const int* in_sizes, int n_in,
                              void* d_out, int out_size, void* d_ws, size_t ws_size,
                              hipStream_t stream) {
    const float* x     = (const float*)d_in[0];
    const float* vqc_w = (const float*)d_in[1];
    const float* fcw   = (const float*)d_in[2];
    const float* fcb   = (const float*)d_in[3];
    float* out = (float*)d_out;

    float* y   = (float*)d_ws;          // [768]
    float* att = y + NPLANES;           // [768]

    mean_kernel<<<NPLANES, 512, 0, stream>>>(x, y);
    vqc_kernel<<<1, 64, 0, stream>>>(y, vqc_w, fcw, fcb, att);
    scale_kernel<<<2048, 256, 0, stream>>>(x, att, out, (long)(NPLANES) * HW4);
}

// Round 3
// 100.045 us; speedup vs baseline: 1.0972x; 1.0972x over previous
//
#include <hip/hip_runtime.h>
#include <math.h>

#define HW 65536            // 256*256 elements per (b,c) plane
#define HW4 16384           // float4 per plane
#define NPLANES 768         // 64*12
#define NSEG 3072           // 4 segments per plane
#define SEG4 4096           // float4 per segment
#define NQ 4
#define NCH 12

typedef float f32x4 __attribute__((ext_vector_type(4)));  // native vector: works with nontemporal builtins

// ---------------- Kernel 1: per-segment partial sum ----------------
// 3072 blocks x 256 threads; each block sums one contiguous quarter-plane.
__global__ __launch_bounds__(256) void mean_partial(const float* __restrict__ x,
                                                    float* __restrict__ part) {
    const int seg = blockIdx.x;
    const f32x4* p = reinterpret_cast<const f32x4*>(x) + (size_t)seg * SEG4;
    const int t = threadIdx.x;
    float s0 = 0.f, s1 = 0.f, s2 = 0.f, s3 = 0.f;
    #pragma unroll
    for (int i = 0; i < 16; i += 4) {
        f32x4 a = p[t + (i + 0) * 256];
        f32x4 b = p[t + (i + 1) * 256];
        f32x4 c = p[t + (i + 2) * 256];
        f32x4 d = p[t + (i + 3) * 256];
        s0 += (a.x + a.y) + (a.z + a.w);
        s1 += (b.x + b.y) + (b.z + b.w);
        s2 += (c.x + c.y) + (c.z + c.w);
        s3 += (d.x + d.y) + (d.z + d.w);
    }
    float sum = (s0 + s1) + (s2 + s3);
    #pragma unroll
    for (int off = 32; off > 0; off >>= 1) sum += __shfl_down(sum, off);
    __shared__ float wsum[4];
    if ((threadIdx.x & 63) == 0) wsum[threadIdx.x >> 6] = sum;
    __syncthreads();
    if (threadIdx.x == 0) part[seg] = (wsum[0] + wsum[1]) + (wsum[2] + wsum[3]);
}

// ---------------- Kernel 2: reduce partials + VQC + FC + sigmoid ----------------
__device__ __forceinline__ void apply_rz(float* sr, float* si, int mask, float theta) {
    float c, s;
    __sincosf(0.5f * theta, &s, &c);
    #pragma unroll
    for (int i = 0; i < 16; ++i) {
        float r = sr[i], im = si[i];
        if (i & mask) {            // e^{+i t/2}
            sr[i] = r * c - im * s;
            si[i] = im * c + r * s;
        } else {                   // e^{-i t/2}
            sr[i] = r * c + im * s;
            si[i] = im * c - r * s;
        }
    }
}

__device__ __forceinline__ void apply_ry(float* sr, float* si, int mask, float theta) {
    float c, s;
    __sincosf(0.5f * theta, &s, &c);
    #pragma unroll
    for (int i = 0; i < 16; ++i) {
        if (i & mask) continue;
        int j = i | mask;
        float r0 = sr[i], i0 = si[i], r1 = sr[j], i1 = si[j];
        sr[i] = c * r0 - s * r1;  si[i] = c * i0 - s * i1;
        sr[j] = s * r0 + c * r1;  si[j] = s * i0 + c * i1;
    }
}

__device__ __forceinline__ void apply_cnot(float* sr, float* si, int mc, int mt) {
    #pragma unroll
    for (int i = 0; i < 16; ++i) {
        if ((i & mc) && !(i & mt)) {
            int j = i | mt;
            float tr = sr[i], ti = si[i];
            sr[i] = sr[j]; si[i] = si[j];
            sr[j] = tr;    si[j] = ti;
        }
    }
}

__device__ __forceinline__ void apply_u3(float* sr, float* si, int mask,
                                         float theta, float phi, float lam) {
    float c = __cosf(0.5f * theta), s = __sinf(0.5f * theta);
    float cl, sl, cp, sp, cpl, spl;
    __sincosf(lam, &sl, &cl);
    __sincosf(phi, &sp, &cp);
    __sincosf(phi + lam, &spl, &cpl);
    float u01r = -cl * s, u01i = -sl * s;
    float u10r =  cp * s, u10i =  sp * s;
    float u11r =  cpl * c, u11i = spl * c;
    #pragma unroll
    for (int i = 0; i < 16; ++i) {
        if (i & mask) continue;
        int j = i | mask;
        float r0 = sr[i], i0 = si[i], r1 = sr[j], i1 = si[j];
        sr[i] = c * r0 + (u01r * r1 - u01i * i1);
        si[i] = c * i0 + (u01r * i1 + u01i * r1);
        sr[j] = (u10r * r0 - u10i * i0) + (u11r * r1 - u11i * i1);
        si[j] = (u10r * i0 + u10i * r0) + (u11r * i1 + u11i * r1);
    }
}

__global__ __launch_bounds__(64) void vqc_kernel(const float* __restrict__ part,  // [3072]
                                                 const float* __restrict__ w,     // [1,4,3]
                                                 const float* __restrict__ fcw,   // [12,4]
                                                 const float* __restrict__ fcb,   // [12]
                                                 float* __restrict__ att) {       // [64,12]
    const int b = threadIdx.x;      // one wave, one thread per batch element
    // reduce 4 partials per plane -> y[b][c]
    const f32x4* pp = reinterpret_cast<const f32x4*>(part);
    float yv[NCH];
    #pragma unroll
    for (int c = 0; c < NCH; ++c) {
        f32x4 v = pp[b * NCH + c];
        yv[c] = ((v.x + v.y) + (v.z + v.w)) * (1.0f / (float)HW);
    }

    float sr[16], si[16];
    #pragma unroll
    for (int i = 0; i < 16; ++i) { sr[i] = 0.25f; si[i] = 0.f; }

    #pragma unroll
    for (int q = 0; q < NQ; ++q) {
        const int mask = 1 << (3 - q);
        apply_rz(sr, si, mask, yv[q * 3 + 0]);
        apply_ry(sr, si, mask, yv[q * 3 + 1]);
        apply_rz(sr, si, mask, yv[q * 3 + 2]);
    }

    apply_cnot(sr, si, 1 << 3, 1 << 2);
    apply_cnot(sr, si, 1 << 2, 1 << 1);
    apply_cnot(sr, si, 1 << 1, 1 << 0);
    apply_cnot(sr, si, 1 << 0, 1 << 3);
    #pragma unroll
    for (int q = 0; q < NQ; ++q) {
        const int mask = 1 << (3 - q);
        apply_u3(sr, si, mask, w[q * 3 + 0], w[q * 3 + 1], w[q * 3 + 2]);
    }

    float z[NQ];
    #pragma unroll
    for (int q = 0; q < NQ; ++q) {
        const int mask = 1 << (3 - q);
        float acc = 0.f;
        #pragma unroll
        for (int i = 0; i < 16; ++i) {
            float p = sr[i] * sr[i] + si[i] * si[i];
            acc += (i & mask) ? -p : p;
        }
        z[q] = acc;
    }

    #pragma unroll
    for (int ch = 0; ch < NCH; ++ch) {
        float a = fcb[ch];
        #pragma unroll
        for (int q = 0; q < NQ; ++q) a += z[q] * fcw[ch * NQ + q];
        att[b * NCH + ch] = 1.0f / (1.0f + expf(-a));
    }
}

// ---------------- Kernel 3: broadcast scale ----------------
__global__ __launch_bounds__(256) void scale_kernel(const float* __restrict__ x,
                                                    const float* __restrict__ att,
                                                    float* __restrict__ out,
                                                    long n4) {
    long i = (long)blockIdx.x * blockDim.x + threadIdx.x;
    const long stride = (long)gridDim.x * blockDim.x;
    const f32x4* xi = reinterpret_cast<const f32x4*>(x);
    f32x4* oi = reinterpret_cast<f32x4*>(out);
    #pragma unroll 4
    for (; i < n4; i += stride) {
        float a = att[i >> 14];     // 16384 float4 per plane; wave-uniform
        f32x4 v = xi[i];
        v *= a;
        __builtin_nontemporal_store(v, &oi[i]);   // out never re-read: skip allocation
    }
}

extern "C" void kernel_launch(void* const* d_in, const int* in_sizes, int n_in,
                              void* d_out, int out_size, void* d_ws, size_t ws_size,
                              hipStream_t stream) {
    const float* x     = (const float*)d_in[0];
    const float* vqc_w = (const float*)d_in[1];
    const float* fcw   = (const float*)d_in[2];
    const float* fcb   = (const float*)d_in[3];
    float* out = (float*)d_out;

    float* part = (float*)d_ws;           // [3072]
    float* att  = part + NSEG;            // [768]

    mean_partial<<<NSEG, 256, 0, stream>>>(x, part);
    vqc_kernel<<<1, 64, 0, stream>>>(part, vqc_w, fcw, fcb, att);
    scale_kernel<<<2048, 256, 0, stream>>>(x, att, out, (long)NPLANES * HW4);
}